// Round 2
// baseline (475.914 us; speedup 1.0000x reference)
//
#include <hip/hip_runtime.h>

// PointPillarScatter: out[b, c, y, x] = feat[p, c] where pillar p sits at (b, y, x), else 0.
// NX=432, NY=496, NZ=1, C=64, B=8 (B derived from out_size).
// Inverse-map approach: cell -> pillar index map in d_ws, then one fully-coalesced
// gather pass writing every output element exactly once (zero or feature).
// R5: unconditional clamped feat loads + load-all-16/store-all-16 (kept).
// R6: PLAIN stores instead of __builtin_nontemporal_store. The nt hint protected
//     L2 for feat reads, but feat is only 33 MB read-once; meanwhile the rocclr
//     fill kernel hits 6.2+ TB/s on this same output buffer with plain stores.
//     If nt was taxing L2 write-combining of our 1KB wave-stores, this recovers it.
//     Single-variable A/B vs R5: everything else byte-identical.

#define NXC   432
#define NYC   496
#define CCH   64
#define PLANE (NXC * NYC)        // 214272 cells per (batch, channel) plane
#define CB    256                // cells per gather block; 214272 = 837 * 256

typedef float vfloat4 __attribute__((ext_vector_type(4)));

__global__ __launch_bounds__(256) void init_map_kernel(int* __restrict__ map, int n4) {
    int i = blockIdx.x * blockDim.x + threadIdx.x;
    if (i < n4) {
        ((int4*)map)[i] = make_int4(-1, -1, -1, -1);
    }
}

__global__ __launch_bounds__(256) void scatter_idx_kernel(const int* __restrict__ coords,
                                                          int* __restrict__ map, int P) {
    int p = blockIdx.x * blockDim.x + threadIdx.x;
    if (p < P) {
        int4 c = ((const int4*)coords)[p];   // [b, z, y, x]
        int flat = c.x * PLANE + (c.y + c.z * NXC + c.w);  // z term is 0 (NZ=1)
        map[flat] = p;
    }
}

// Block = 256 cells x 64 channels. Wave w (0..3) owns channels [16w, 16w+16),
// lane l (0..63) owns cells [4l, 4l+4). All 16 feat fragments loaded up-front,
// unconditionally (empty cells clamp to pillar row 0, zeroed afterward with
// cndmask) -> no exec-masked loads, static vmcnt counting, deep pipelining.
__global__ __launch_bounds__(256) void gather_kernel(const float* __restrict__ feat,
                                                     const int* __restrict__ map,
                                                     float* __restrict__ out, int P) {
    const int tid   = threadIdx.x;
    const int w     = tid >> 6;                      // wave -> channel group base 16w
    const int l     = tid & 63;                      // lane -> cell group
    const int bpb   = PLANE / CB;                    // 837 blocks per batch
    const int cb    = blockIdx.x % bpb;
    const int b     = blockIdx.x / bpb;
    const int cell0 = cb * CB;

    // coalesced map read: 64 lanes x int4 = 1 KB (waves share lines via L1)
    const int4 pm = ((const int4*)(map + (unsigned)(b * PLANE) + cell0))[l];
    const unsigned uP = (unsigned)P;

    const int idxr[4] = { pm.x, pm.y, pm.z, pm.w };
    bool     occ[4];
    unsigned foff[4];                                // float offsets, 32-bit
    #pragma unroll
    for (int i = 0; i < 4; ++i) {
        occ[i]  = ((unsigned)idxr[i] < uP);
        // clamp empty cells to pillar row 0: always-valid address, all inactive
        // lanes hit the SAME 16B -> coalesced broadcast, ~free.
        foff[i] = (occ[i] ? (unsigned)idxr[i] : 0u) * (unsigned)CCH + (unsigned)(w * 16);
    }

    // ---- load all 16 fragments (4 cells x 4 channel-chunks), unconditional ----
    vfloat4 s[4][4];
    #pragma unroll
    for (int i = 0; i < 4; ++i) {
        #pragma unroll
        for (int k = 0; k < 4; ++k) {
            s[i][k] = *(const vfloat4*)(feat + foff[i] + (unsigned)(4 * k));
        }
    }

    // ---- branchless zeroing of empty cells (v_cndmask, no memory ops) ----
    const vfloat4 z = (vfloat4)(0.f);
    #pragma unroll
    for (int i = 0; i < 4; ++i) {
        #pragma unroll
        for (int k = 0; k < 4; ++k) {
            s[i][k] = occ[i] ? s[i][k] : z;
        }
    }

    // out offset fits 32-bit: max (496 planes)*214272*4B = 425 MB
    float* obase = out + (size_t)((unsigned)(b * CCH + w * 16) * (unsigned)PLANE
                                  + (unsigned)(cell0 + 4 * l));

    // ---- transpose 4x4 per chunk, 4 plain 1KB wave-stores per chunk ----
    #pragma unroll
    for (int k = 0; k < 4; ++k) {
        vfloat4 t0 = { s[0][k].x, s[1][k].x, s[2][k].x, s[3][k].x };
        vfloat4 t1 = { s[0][k].y, s[1][k].y, s[2][k].y, s[3][k].y };
        vfloat4 t2 = { s[0][k].z, s[1][k].z, s[2][k].z, s[3][k].z };
        vfloat4 t3 = { s[0][k].w, s[1][k].w, s[2][k].w, s[3][k].w };
        float* o = obase + (size_t)(4 * k) * PLANE;
        *(vfloat4*)(o)              = t0;
        *(vfloat4*)(o + 1L * PLANE) = t1;
        *(vfloat4*)(o + 2L * PLANE) = t2;
        *(vfloat4*)(o + 3L * PLANE) = t3;
    }
}

extern "C" void kernel_launch(void* const* d_in, const int* in_sizes, int n_in,
                              void* d_out, int out_size, void* d_ws, size_t ws_size,
                              hipStream_t stream) {
    const float* x0     = (const float*)d_in[0];
    const int*   coords = (const int*)d_in[1];
    float*       out    = (float*)d_out;

    const int P = in_sizes[0] / CCH;                 // 128000 pillars
    const int B = out_size / (CCH * PLANE);          // 8

    int* map = (int*)d_ws;                           // B*PLANE int32 = 6.86 MB scratch

    // 1) init map to -1 (any value with (unsigned)v >= P marks empty)
    const int n4 = (B * PLANE) / 4;
    init_map_kernel<<<(n4 + 255) / 256, 256, 0, stream>>>(map, n4);

    // 2) scatter pillar index into map
    scatter_idx_kernel<<<(P + 255) / 256, 256, 0, stream>>>(coords, map, P);

    // 3) gather pass: write full output, fully coalesced, float4-wide
    const int nblocks = B * (PLANE / CB);            // 6696
    gather_kernel<<<nblocks, 256, 0, stream>>>(x0, map, out, P);
}

// Round 3
// 457.523 us; speedup vs baseline: 1.0402x; 1.0402x over previous
//
#include <hip/hip_runtime.h>

// PointPillarScatter: out[b, c, y, x] = feat[p, c] where pillar p sits at (b, y, x), else 0.
// NX=432, NY=496, NZ=1, C=64, B=8 (B derived from out_size).
// Inverse-map approach: cell -> pillar index map in d_ws, then one fully-coalesced
// gather pass writing every output element exactly once (zero or feature).
// R5: unconditional clamped feat loads + load-all-16/store-all-16 + NT stores. 459.8 us.
// R6: A/B'd plain stores vs NT -> REGRESSED to 475.9 us. NT stores keep the 439 MB
//     streamed output out of L2/L3 (protects map+feat working set) and write-combine
//     better for our 1KB-granule plane-strided store pattern. Conclusion: NT is load-
//     bearing here, not a tax.
// R7: revert to R5 exactly (best measured). No new variable.

#define NXC   432
#define NYC   496
#define CCH   64
#define PLANE (NXC * NYC)        // 214272 cells per (batch, channel) plane
#define CB    256                // cells per gather block; 214272 = 837 * 256

typedef float vfloat4 __attribute__((ext_vector_type(4)));

__global__ __launch_bounds__(256) void init_map_kernel(int* __restrict__ map, int n4) {
    int i = blockIdx.x * blockDim.x + threadIdx.x;
    if (i < n4) {
        ((int4*)map)[i] = make_int4(-1, -1, -1, -1);
    }
}

__global__ __launch_bounds__(256) void scatter_idx_kernel(const int* __restrict__ coords,
                                                          int* __restrict__ map, int P) {
    int p = blockIdx.x * blockDim.x + threadIdx.x;
    if (p < P) {
        int4 c = ((const int4*)coords)[p];   // [b, z, y, x]
        int flat = c.x * PLANE + (c.y + c.z * NXC + c.w);  // z term is 0 (NZ=1)
        map[flat] = p;
    }
}

// Block = 256 cells x 64 channels. Wave w (0..3) owns channels [16w, 16w+16),
// lane l (0..63) owns cells [4l, 4l+4). All 16 feat fragments loaded up-front,
// unconditionally (empty cells clamp to pillar row 0, zeroed afterward with
// cndmask) -> no exec-masked loads, static vmcnt counting, deep pipelining.
__global__ __launch_bounds__(256) void gather_kernel(const float* __restrict__ feat,
                                                     const int* __restrict__ map,
                                                     float* __restrict__ out, int P) {
    const int tid   = threadIdx.x;
    const int w     = tid >> 6;                      // wave -> channel group base 16w
    const int l     = tid & 63;                      // lane -> cell group
    const int bpb   = PLANE / CB;                    // 837 blocks per batch
    const int cb    = blockIdx.x % bpb;
    const int b     = blockIdx.x / bpb;
    const int cell0 = cb * CB;

    // coalesced map read: 64 lanes x int4 = 1 KB (waves share lines via L1)
    const int4 pm = ((const int4*)(map + (unsigned)(b * PLANE) + cell0))[l];
    const unsigned uP = (unsigned)P;

    const int idxr[4] = { pm.x, pm.y, pm.z, pm.w };
    bool     occ[4];
    unsigned foff[4];                                // float offsets, 32-bit
    #pragma unroll
    for (int i = 0; i < 4; ++i) {
        occ[i]  = ((unsigned)idxr[i] < uP);
        // clamp empty cells to pillar row 0: always-valid address, all inactive
        // lanes hit the SAME 16B -> coalesced broadcast, ~free.
        foff[i] = (occ[i] ? (unsigned)idxr[i] : 0u) * (unsigned)CCH + (unsigned)(w * 16);
    }

    // ---- load all 16 fragments (4 cells x 4 channel-chunks), unconditional ----
    vfloat4 s[4][4];
    #pragma unroll
    for (int i = 0; i < 4; ++i) {
        #pragma unroll
        for (int k = 0; k < 4; ++k) {
            s[i][k] = *(const vfloat4*)(feat + foff[i] + (unsigned)(4 * k));
        }
    }

    // ---- branchless zeroing of empty cells (v_cndmask, no memory ops) ----
    const vfloat4 z = (vfloat4)(0.f);
    #pragma unroll
    for (int i = 0; i < 4; ++i) {
        #pragma unroll
        for (int k = 0; k < 4; ++k) {
            s[i][k] = occ[i] ? s[i][k] : z;
        }
    }

    // out offset fits 32-bit: max (496 planes)*214272*4B = 425 MB
    float* obase = out + (size_t)((unsigned)(b * CCH + w * 16) * (unsigned)PLANE
                                  + (unsigned)(cell0 + 4 * l));

    // ---- transpose 4x4 per chunk, 4 nontemporal 1KB wave-stores per chunk ----
    #pragma unroll
    for (int k = 0; k < 4; ++k) {
        vfloat4 t0 = { s[0][k].x, s[1][k].x, s[2][k].x, s[3][k].x };
        vfloat4 t1 = { s[0][k].y, s[1][k].y, s[2][k].y, s[3][k].y };
        vfloat4 t2 = { s[0][k].z, s[1][k].z, s[2][k].z, s[3][k].z };
        vfloat4 t3 = { s[0][k].w, s[1][k].w, s[2][k].w, s[3][k].w };
        float* o = obase + (size_t)(4 * k) * PLANE;
        __builtin_nontemporal_store(t0, (vfloat4*)(o));
        __builtin_nontemporal_store(t1, (vfloat4*)(o + 1L * PLANE));
        __builtin_nontemporal_store(t2, (vfloat4*)(o + 2L * PLANE));
        __builtin_nontemporal_store(t3, (vfloat4*)(o + 3L * PLANE));
    }
}

extern "C" void kernel_launch(void* const* d_in, const int* in_sizes, int n_in,
                              void* d_out, int out_size, void* d_ws, size_t ws_size,
                              hipStream_t stream) {
    const float* x0     = (const float*)d_in[0];
    const int*   coords = (const int*)d_in[1];
    float*       out    = (float*)d_out;

    const int P = in_sizes[0] / CCH;                 // 128000 pillars
    const int B = out_size / (CCH * PLANE);          // 8

    int* map = (int*)d_ws;                           // B*PLANE int32 = 6.86 MB scratch

    // 1) init map to -1 (any value with (unsigned)v >= P marks empty)
    const int n4 = (B * PLANE) / 4;
    init_map_kernel<<<(n4 + 255) / 256, 256, 0, stream>>>(map, n4);

    // 2) scatter pillar index into map
    scatter_idx_kernel<<<(P + 255) / 256, 256, 0, stream>>>(coords, map, P);

    // 3) gather pass: write full output, fully coalesced, float4-wide, nontemporal
    const int nblocks = B * (PLANE / CB);            // 6696
    gather_kernel<<<nblocks, 256, 0, stream>>>(x0, map, out, P);
}